// Round 1
// baseline (15.910 us; speedup 1.0000x reference)
//
#include <hip/hip_runtime.h>
#include <math.h>

#define HID 5
#define NTAB 27

__device__ __forceinline__ float sigm(float x) { return 1.0f / (1.0f + expf(-x)); }
__device__ __forceinline__ float softplus_f(float x) {
    // numerically-stable log1p(exp(x)) to match jax.nn.softplus
    return fmaxf(x, 0.0f) + log1pf(expf(-fabsf(x)));
}

__device__ __forceinline__ float sample_out(const float* __restrict__ tab,
                                            float x, float l, float g) {
    int sx = (x > 0.0f) - (x < 0.0f);
    int sl = (l > 0.0f) - (l < 0.0f);
    int sg = (g > 0.0f) - (g < 0.0f);
    float ax = fabsf(x);
    float scale = (ax > 0.0f) ? ax : 1.0f;
    return tab[(sx + 1) * 9 + (sl + 1) * 3 + (sg + 1)] * scale;
}

__global__ __launch_bounds__(256) void lstm_opt_kernel(
    const float* __restrict__ bx, const float* __restrict__ bl, const float* __restrict__ bg,
    const float* __restrict__ W_ih1, const float* __restrict__ W_hh1,
    const float* __restrict__ b_ih1, const float* __restrict__ b_hh1,
    const float* __restrict__ W_ih2, const float* __restrict__ W_hh2,
    const float* __restrict__ b_ih2, const float* __restrict__ b_hh2,
    const float* __restrict__ W_out, const float* __restrict__ b_out,
    const float* __restrict__ h1_0, const float* __restrict__ c1_0,
    const float* __restrict__ h2_0, const float* __restrict__ c2_0,
    const float* __restrict__ poly, const int* __restrict__ t_ptr,
    float* __restrict__ out, int N)
{
    __shared__ float s_table[NTAB];
    const int tid = threadIdx.x;

    // ---- per-block setup: 27-entry LUT over (sign(bx),sign(bl),sign(bg)) ----
    if (tid < NTAB) {
        float gn = (float)(tid % 3) - 1.0f;
        float ln = (float)((tid / 3) % 3) - 1.0f;
        float xn = (float)(tid / 9) - 1.0f;

        // LSTM cell 1 (input u = [xn, ln, gn], state h1_0/c1_0 broadcast)
        float h1[HID];
        for (int j = 0; j < HID; ++j) {
            float gk[4];
            #pragma unroll
            for (int q = 0; q < 4; ++q) {
                int k = j + q * HID;
                float acc = b_ih1[k] + b_hh1[k];
                #pragma unroll
                for (int m = 0; m < HID; ++m) acc += W_hh1[k * HID + m] * h1_0[m];
                acc += W_ih1[k * 3 + 0] * xn + W_ih1[k * 3 + 1] * ln + W_ih1[k * 3 + 2] * gn;
                gk[q] = acc;
            }
            float c = sigm(gk[1]) * c1_0[j] + sigm(gk[0]) * tanhf(gk[2]);
            h1[j] = sigm(gk[3]) * tanhf(c);
        }

        // LSTM cell 2 (input h1, state h2_0/c2_0 broadcast)
        float h2v[HID];
        for (int j = 0; j < HID; ++j) {
            float gk[4];
            #pragma unroll
            for (int q = 0; q < 4; ++q) {
                int k = j + q * HID;
                float acc = b_ih2[k] + b_hh2[k];
                #pragma unroll
                for (int m = 0; m < HID; ++m) acc += W_hh2[k * HID + m] * h2_0[m];
                #pragma unroll
                for (int m = 0; m < HID; ++m) acc += W_ih2[k * HID + m] * h1[m];
                gk[q] = acc;
            }
            float c = sigm(gk[1]) * c2_0[j] + sigm(gk[0]) * tanhf(gk[2]);
            h2v[j] = sigm(gk[3]) * tanhf(c);
        }

        // output head
        float v = b_out[0];
        #pragma unroll
        for (int m = 0; m < HID; ++m) v += W_out[m] * h2v[m];

        // poly_value * gamma^t folded into the table
        int t = *t_ptr;
        float tf = (float)t;
        float pv = 0.0f, p = 1.0f;   // p = t^j with 0^0 == 1 (matches Python)
        #pragma unroll
        for (int jj = 0; jj < 4; ++jj) { pv += softplus_f(poly[jj]) * p; p *= tf; }
        float gt = powf(0.99f, tf);

        s_table[tid] = pv * gt * tanhf(v);
    }
    __syncthreads();

    // ---- streaming main loop: pure memory-bound ----
    const int gtid = blockIdx.x * blockDim.x + tid;
    const int gstride = gridDim.x * blockDim.x;
    const int nvec = N >> 2;

    const float4* bx4 = reinterpret_cast<const float4*>(bx);
    const float4* bl4 = reinterpret_cast<const float4*>(bl);
    const float4* bg4 = reinterpret_cast<const float4*>(bg);
    float4* out4 = reinterpret_cast<float4*>(out);

    for (int i = gtid; i < nvec; i += gstride) {
        float4 x = bx4[i];
        float4 l = bl4[i];
        float4 g = bg4[i];
        float4 o;
        o.x = sample_out(s_table, x.x, l.x, g.x);
        o.y = sample_out(s_table, x.y, l.y, g.y);
        o.z = sample_out(s_table, x.z, l.z, g.z);
        o.w = sample_out(s_table, x.w, l.w, g.w);
        out4[i] = o;
    }
    // tail (N % 4)
    for (int i = (nvec << 2) + gtid; i < N; i += gstride) {
        out[i] = sample_out(s_table, bx[i], bl[i], bg[i]);
    }
}

extern "C" void kernel_launch(void* const* d_in, const int* in_sizes, int n_in,
                              void* d_out, int out_size, void* d_ws, size_t ws_size,
                              hipStream_t stream) {
    const float* bx    = (const float*)d_in[0];
    const float* bl    = (const float*)d_in[1];
    const float* bg    = (const float*)d_in[2];
    const float* W_ih1 = (const float*)d_in[3];
    const float* W_hh1 = (const float*)d_in[4];
    const float* b_ih1 = (const float*)d_in[5];
    const float* b_hh1 = (const float*)d_in[6];
    const float* W_ih2 = (const float*)d_in[7];
    const float* W_hh2 = (const float*)d_in[8];
    const float* b_ih2 = (const float*)d_in[9];
    const float* b_hh2 = (const float*)d_in[10];
    const float* W_out = (const float*)d_in[11];
    const float* b_out = (const float*)d_in[12];
    const float* h1_0  = (const float*)d_in[13];
    const float* c1_0  = (const float*)d_in[14];
    const float* h2_0  = (const float*)d_in[15];
    const float* c2_0  = (const float*)d_in[16];
    const float* poly  = (const float*)d_in[17];
    const int*   t_ptr = (const int*)d_in[18];
    float* out = (float*)d_out;

    int N = in_sizes[0];
    int nvec = N >> 2;
    int blocks = (nvec + 255) / 256;
    if (blocks < 1) blocks = 1;
    if (blocks > 2048) blocks = 2048;

    lstm_opt_kernel<<<blocks, 256, 0, stream>>>(
        bx, bl, bg, W_ih1, W_hh1, b_ih1, b_hh1,
        W_ih2, W_hh2, b_ih2, b_hh2, W_out, b_out,
        h1_0, c1_0, h2_0, c2_0, poly, t_ptr, out, N);
}